// Round 9
// baseline (151.858 us; speedup 1.0000x reference)
//
#include <hip/hip_runtime.h>

// Problem constants (fixed in the reference file)
#define OHh   60
#define OWw   60
#define NBINS (OHh * OWw)   // 3600
#define NB    64            // batches
#define NS    4096          // spikes per batch
#define CAP   128

#define NW     4            // waves per block
#define SEG    (NS / NW)    // 1024 spikes scanned per wave
#define CH     (SEG / 64)   // 16 chunks per wave
#define WSLOTS 36           // staged slots/segment/bin (+1 dummy). Poisson(6.25): P(>36)~1e-17
#define PRE0   64           // slots [PRE0,CAP) prefilled -1 during scan (P(total>64)~1e-11)
#define GH     12           // hits per pair-group: 12 hits x 5 kw = 60 pair-lanes

// One 4-wave block per (batch, output row); lane == ow in the bin domain.
// R8 post-mortem: bound by LDS-pipe work (~11 DS wave-instrs/chunk, ~26 us/CU);
// per-hit stage writes used only 5/64 lanes. R9 transposes the hit loop:
// pair-lane p = 5*i + kw processes (hit i, offset kw) -> bin ow = w_i - kw,
// val = A_i + kw. Per chunk the DS cost is 5 wave-instrs TOTAL (hitbuf write,
// pair gather, cnt read, ONE scattered stage write covering ~25 incidences,
// cnt write) vs ~11. s-order preserved: slot = cnt[ow] + rank, rank = # of
// earlier same-chunk hits covering ow (uniform readlane loop, lane order ==
// s order); cnt carries across chunks in LDS. Dump + prefill unchanged
// (contiguous 240B runs, WRITE_SIZE ~= 1.0x output).
__global__ __launch_bounds__(256) void sort_spikes_row4(
    const int* __restrict__ spikes, int* __restrict__ out) {
    const int bid  = (int)blockIdx.x;
    const int b    = bid & (NB - 1);   // batch-minor -> batch b pinned to XCD b%8
    const int row  = bid >> 6;         // output row oh, 0..59
    const int tid  = (int)threadIdx.x;
    const int wv   = tid >> 6;
    const int lane = tid & 63;
    const bool valid = lane < OWw;

    // Pair decomposition (constants per lane). Lanes 60..63: i_loc=12 -> never active.
    const int i_loc = lane / 5;
    const int kw_p  = lane - 5 * i_loc;

    __shared__ short        stage[NW][WSLOTS + 1][64];  // 18944 B (+1 dummy sink row)
    __shared__ unsigned int hbuf[NW][64];               // compacted chunk payloads
    __shared__ int          cnt[NW][64];                // per-seg per-bin counts (60 sink for parked)
    __shared__ int          ovf;

    if (tid == 0) ovf = 0;
    cnt[wv][lane] = 0;                 // own-wave data only; no barrier needed yet

    const int* __restrict__ sp   = spikes + b * NS + wv * SEG;
    int* __restrict__       outb = out + (size_t)b * (CAP * NBINS) + row * OWw;

    // Issue all 16 chunk loads up front (deep vmcnt pipeline; L2-resident
    // after the first of a batch's 60 blocks touches them).
    int vs[CH];
#pragma unroll
    for (int c = 0; c < CH; ++c) vs[c] = sp[c * 64 + lane];

    unsigned int* const hb = &hbuf[wv][0];
    int* const          cw = &cnt[wv][0];

#pragma unroll
    for (int c = 0; c < CH; ++c) {
        const int v    = vs[c];
        const int kh   = ((v >> 6) & 63) - row;
        const bool halo = (unsigned)kh < 5u;
        const int w    = v & 63;
        // payload: w in [31:16], A = c*25+kh*5 (<=795) in [15:0]
        const unsigned P = ((unsigned)w << 16) | (unsigned)((v >> 12) * 25 + kh * 5);

        const unsigned long long mask = __ballot(halo);
        const int pos = __builtin_amdgcn_mbcnt_hi(
            (unsigned)(mask >> 32),
            __builtin_amdgcn_mbcnt_lo((unsigned)mask, 0));  // rank among halo lanes
        if (halo) hb[pos] = P;                              // s-order preserved
        const int n = __popcll(mask);

        for (int g = 0; g < n; g += GH) {      // 1 group w.p. ~99.8%
            const int  ghits = min(n - g, GH);
            const bool pact  = i_loc < ghits;
            const int  hidx  = pact ? (g + i_loc) : 0;
            const unsigned Pi = hb[hidx];      // ds_read_b32: <=12 addrs, 5-way broadcast
            const int wi = (int)(Pi >> 16);
            const int Ai = (int)(Pi & 0xffffu);
            const int ow = wi - kw_p;                      // target bin
            const bool act = pact & ((unsigned)ow < (unsigned)OWw);

            // rank = # earlier same-group hits covering ow; full = all such hits
            int rank = 0, full = 0;
            for (int t = 0; t < ghits; ++t) {              // uniform trip count
                const unsigned Pt = __builtin_amdgcn_readlane(Pi, 5 * t);  // hit g+t payload
                const bool cond = (unsigned)((int)(Pt >> 16) - ow) < 5u;
                full += cond;
                rank += (cond & (t < i_loc));
            }

            const int ow_c = act ? ow : 60;                // sink index for inactive
            const int base = cw[ow_c];                     // ds_read_b32
            int slot = base + rank;
            const bool ok = act & (slot < WSLOTS);
            slot = ok ? slot : WSLOTS;                     // dummy row
            // ONE scattered stage write for all ~25 incidences. bank = ow/2 (~2-way).
            stage[wv][slot][act ? ow : lane] = (short)(Ai + kw_p);
            // same-ow lanes write identical base+full -> benign duplicate
            cw[ow_c] = base + (act ? full : 0);            // ds_write_b32
        }

        // Hidden write: one -1 slot-row per chunk -> slots [64,128) done by
        // scan end. Contiguous 240 B run, paced under the scan.
        if (valid) outb[(PRE0 + wv * CH + c) * NBINS + lane] = -1;
    }

    const int count = cw[lane];                            // own-seg per-bin total
    if (__ballot(valid && count > WSLOTS) && lane == 0) ovf = 1;  // benign multi-write
    __syncthreads();

    if (ovf == 0) {
        if (valid) {
            const int c0 = cnt[0][lane], c1 = cnt[1][lane];
            const int c2 = cnt[2][lane], c3 = cnt[3][lane];
            const int o1 = c0, o2 = c0 + c1, o3 = o2 + c2;
            const int total = o3 + c3;
            // Dump slots [0,64): 16 per wave, wave order == s order.
#pragma unroll 4
            for (int i = 0; i < PRE0 / NW; ++i) {
                const int k = wv * (PRE0 / NW) + i;
                int val = -1;
                if (k < total) {
                    int wsel = 0, base = 0;
                    if (k >= o1) { wsel = 1; base = o1; }
                    if (k >= o2) { wsel = 2; base = o2; }
                    if (k >= o3) { wsel = 3; base = o3; }
                    val = (int)stage[wsel][k - base][lane];  // bank=lane>>1, free
                }
                outb[k * NBINS + lane] = val;              // contiguous 240 B run
            }
            // Astronomically rare: overwrite prefilled -1s with real values.
            for (int k = PRE0 + wv; k < total && k < CAP; k += NW) {
                int wsel = 0, base = 0;
                if (k >= o1) { wsel = 1; base = o1; }
                if (k >= o2) { wsel = 2; base = o2; }
                if (k >= o3) { wsel = 3; base = o3; }
                outb[k * NBINS + lane] = (int)stage[wsel][k - base][lane];
            }
        }
    } else if (wv == 0) {
        // Fallback: >36 staged hits in one bin from one 1024-spike segment
        // (P ~ 1e-17 random input). Serial redo, direct global stores.
        const int* __restrict__ spf = spikes + b * NS;
        const int lane_c = valid ? lane : 127;
        int cc = 0;
        for (int c = 0; c < NS / 64; ++c) {
            const int v = spf[c * 64 + lane];
            const int h = (v >> 6) & 63;
            unsigned long long mask = __ballot((unsigned)(h - row) < 5u);
            while (mask) {
                const int j = (int)__builtin_ctzll(mask);
                mask &= mask - 1;
                const int vj =
                    __builtin_amdgcn_readlane(v, __builtin_amdgcn_readfirstlane(j));
                const int wj  = vj & 63;
                const int khj = ((vj >> 6) & 63) - row;
                const int cj  = vj >> 12;
                const int kw  = wj - lane_c;
                if ((unsigned)kw < 5u) {
                    if (cc < CAP)
                        outb[cc * NBINS + lane] = cj * 25 + khj * 5 + kw;
                    ++cc;
                }
            }
        }
        if (valid)
            for (int k = cc; k < CAP; ++k) outb[k * NBINS + lane] = -1;
    }
}

extern "C" void kernel_launch(void* const* d_in, const int* in_sizes, int n_in,
                              void* d_out, int out_size, void* d_ws, size_t ws_size,
                              hipStream_t stream) {
    const int* spikes = (const int*)d_in[0];  // (B, S, 1, 1) int32
    // d_in[1] (indices table) unused: membership is pure arithmetic.
    int* out = (int*)d_out;                   // (B, CAP, OH, OW) int32

    dim3 grid(OHh * NB);                      // 3840 blocks, batch-minor
    dim3 block(256);                          // 4 waves/block
    sort_spikes_row4<<<grid, block, 0, stream>>>(spikes, out);
}

// Round 10
// 147.465 us; speedup vs baseline: 1.0298x; 1.0298x over previous
//
#include <hip/hip_runtime.h>

// Problem constants (fixed in the reference file)
#define OHh   60
#define OWw   60
#define NBINS (OHh * OWw)   // 3600
#define NB    64            // batches
#define NS    4096          // spikes per batch
#define CAP   128

#define NW     4            // waves per block
#define SEG    (NS / NW)    // 1024 spikes scanned per wave
#define CH     (SEG / 64)   // 16 chunks per wave
#define WSLOTS 40           // staged slots per wave-segment per bin (+1 dummy row)
#define PRE0   40           // slots [PRE0, CAP) prefilled -1 during scan.
                            // total ~ Poisson(25): P(>40) ~ 2e-3 per bin; the
                            // post-barrier guarded overwrite handles those.

// One 4-wave block per (batch, output row); lane == ow (lanes 60..63 parked).
// R9 post-mortem: transposed hit loop regressed (serial 12x readlane rank
// chain per chunk) -> reverted to R8's scan (LDS compaction + broadcast
// ds_read_u16 per hit). R10 deepens R8's hidden prefill from slots [64,128)
// to [40,128): 81 MB of -1 rows streamed under the ~26 us scan (3.1 TB/s,
// below the 6.7 TB/s ceiling), post-barrier dump shrinks to slots [0,40)
// (~37 MB). Slots in [40, total) (P ~ 2e-3/bin) are fixed by the guarded
// overwrite loop after the barrier (vmcnt-drain at __syncthreads orders the
// prefill stores before the overwrites through the same XCD L2).
__global__ __launch_bounds__(256) void sort_spikes_row4(
    const int* __restrict__ spikes, int* __restrict__ out) {
    const int bid  = (int)blockIdx.x;
    const int b    = bid & (NB - 1);   // batch-minor -> batch b pinned to XCD b%8
    const int row  = bid >> 6;         // output row oh, 0..59
    const int tid  = (int)threadIdx.x;
    const int wv   = tid >> 6;
    const int lane = tid & 63;
    const bool valid  = lane < OWw;
    const int  lane_c = valid ? lane : 127;  // parked lanes: window test auto-fails

    __shared__ short          stage[NW][WSLOTS + 1][64];  // 20992 B (+1 dummy sink)
    __shared__ unsigned short hits[NW][64];               // compacted chunk payloads
    __shared__ int            cnt[NW][64];
    __shared__ int            ovf;

    if (tid == 0) ovf = 0;

    const int* __restrict__ sp   = spikes + b * NS + wv * SEG;
    int* __restrict__       outb = out + (size_t)b * (CAP * NBINS) + row * OWw;

    // Issue all 16 chunk loads up front (deep vmcnt pipeline; L2-resident
    // after the first of a batch's 60 blocks touches them).
    int vs[CH];
#pragma unroll
    for (int c = 0; c < CH; ++c) vs[c] = sp[c * 64 + lane];

    unsigned short* const hitbuf      = &hits[wv][0];
    short* const          stage_lane  = &stage[wv][0][lane];      // + count*64 shorts
    short* const          stage_dummy = &stage[wv][WSLOTS][lane]; // sink row

    int count = 0;
#pragma unroll
    for (int c = 0; c < CH; ++c) {
        const int v   = vs[c];
        const int kh  = ((v >> 6) & 63) - row;
        const bool halo = (unsigned)kh < 5u;
        const int w   = v & 63;
        const int A   = (v >> 12) * 25 + kh * 5 + w;  // ckk_base + w, fits 10 bits
        const unsigned short P = (unsigned short)((w << 10) | A);

        const unsigned long long mask = __ballot(halo);   // wave-uniform
        const int pos = __builtin_amdgcn_mbcnt_hi(
            (unsigned)(mask >> 32),
            __builtin_amdgcn_mbcnt_lo((unsigned)mask, 0));  // rank among halo lanes
        if (halo) hitbuf[pos] = P;                          // s-order preserved
        const int n = __popcll(mask);                       // uniform

        for (int i = 0; i < n; ++i) {            // uniform trip count
            const int Pj  = (int)hitbuf[i];      // ds_read_u16 same-addr broadcast
            const int kw  = (Pj >> 10) - lane_c; // per-lane window offset
            const bool inwin = (unsigned)kw < 5u;
            const int val = (Pj & 0x3ff) - lane_c;           // == ckk when inwin
            short* a = (inwin & (count < WSLOTS))
                           ? (stage_lane + count * 64)       // count*128 B
                           : stage_dummy;
            *a = (short)val;                      // garbage to sink is fine
            count += inwin;
        }

        // Hidden writes: -1 slot-rows streamed under the scan.
        // Range [PRE0+64, 128) needs 24 extra rows -> chunks 0..5 write two.
        if (valid) {
            outb[(PRE0 + wv * CH + c) * NBINS + lane] = -1;      // 40..103
            if (c < 6)
                outb[(PRE0 + 64 + wv * 6 + c) * NBINS + lane] = -1;  // 104..127
        }
    }
    cnt[wv][lane] = count;
    if (__ballot(count > WSLOTS) && lane == 0) ovf = 1;  // benign multi-write
    __syncthreads();

    if (ovf == 0) {
        if (valid) {
            const int c0 = cnt[0][lane], c1 = cnt[1][lane];
            const int c2 = cnt[2][lane], c3 = cnt[3][lane];
            const int o1 = c0, o2 = c0 + c1, o3 = o2 + c2;
            const int total = o3 + c3;                 // <=160
            // Dump slots [0,40): 10 per wave, wave order == s order.
#pragma unroll 2
            for (int i = 0; i < PRE0 / NW; ++i) {
                const int k = wv * (PRE0 / NW) + i;
                int val = -1;
                if (k < total) {
                    int wsel = 0, base = 0;
                    if (k >= o1) { wsel = 1; base = o1; }
                    if (k >= o2) { wsel = 2; base = o2; }
                    if (k >= o3) { wsel = 3; base = o3; }
                    val = (int)stage[wsel][k - base][lane];  // bank=lane>>1, free
                }
                outb[k * NBINS + lane] = val;          // contiguous 240 B run
            }
            // Occasionally taken (P ~ 2e-3/bin): overwrite prefilled -1s with
            // real staged values for slots in [PRE0, total).
            for (int k = PRE0 + wv; k < total && k < CAP; k += NW) {
                int wsel = 0, base = 0;
                if (k >= o1) { wsel = 1; base = o1; }
                if (k >= o2) { wsel = 2; base = o2; }
                if (k >= o3) { wsel = 3; base = o3; }
                outb[k * NBINS + lane] = (int)stage[wsel][k - base][lane];
            }
        }
    } else if (wv == 0) {
        // Fallback: >40 staged hits in one bin from one 1024-spike segment
        // (P ~ 1e-22 random input). Serial redo, direct global stores.
        const int* __restrict__ spf = spikes + b * NS;
        int cc = 0;
        for (int c = 0; c < NS / 64; ++c) {
            const int v = spf[c * 64 + lane];
            const int h = (v >> 6) & 63;
            unsigned long long mask = __ballot((unsigned)(h - row) < 5u);
            while (mask) {
                const int j = (int)__builtin_ctzll(mask);
                mask &= mask - 1;
                const int vj =
                    __builtin_amdgcn_readlane(v, __builtin_amdgcn_readfirstlane(j));
                const int wj  = vj & 63;
                const int khj = ((vj >> 6) & 63) - row;
                const int cj  = vj >> 12;
                const int kw  = wj - lane_c;
                if ((unsigned)kw < 5u) {
                    if (cc < CAP)
                        outb[cc * NBINS + lane] = cj * 25 + khj * 5 + kw;
                    ++cc;
                }
            }
        }
        if (valid)
            for (int k = cc; k < CAP; ++k) outb[k * NBINS + lane] = -1;
    }
}

extern "C" void kernel_launch(void* const* d_in, const int* in_sizes, int n_in,
                              void* d_out, int out_size, void* d_ws, size_t ws_size,
                              hipStream_t stream) {
    const int* spikes = (const int*)d_in[0];  // (B, S, 1, 1) int32
    // d_in[1] (indices table) unused: membership is pure arithmetic.
    int* out = (int*)d_out;                   // (B, CAP, OH, OW) int32

    dim3 grid(OHh * NB);                      // 3840 blocks, batch-minor
    dim3 block(256);                          // 4 waves/block
    sort_spikes_row4<<<grid, block, 0, stream>>>(spikes, out);
}